// Round 6
// baseline (1599.988 us; speedup 1.0000x reference)
//
#include <hip/hip_runtime.h>
#include <hip/hip_bf16.h>
#include <stdint.h>

#define N_NODES 100000
#define N_EDGES 1600000
#define D_FEAT 32
#define CUT_K 320000        // int(N_EDGES * 0.2)
#define HIST_NB 1024        // grid-stride blocks for coskey
#define HC_NB 1000          // histc blocks; E = HC_NB * HC_SLICE exactly
#define HC_SLICE 1600
#define SCAN_NB ((N_NODES + 255) / 256)   // 391

struct SelState { unsigned long long prefix; unsigned int k; };

// ---- elected-last-block 256-bin scan, fused into histogram kernels ----
// Each thread merges its bin count into ghist; the last block to finish
// re-reads ghist (atomic = L2-coherent), finds the digit containing rank k,
// updates st, and zeroes ghist for the next pass. Stream ordering makes the
// update visible to the next kernel.
__device__ __forceinline__ void hist_merge_scan(unsigned int tot,
                                                unsigned int* ghist,
                                                unsigned int* done,
                                                SelState* st) {
    int t = threadIdx.x;
    if (tot) atomicAdd(&ghist[t], tot);
    __threadfence();
    __shared__ int isLast;
    __syncthreads();
    if (t == 0) {
        unsigned int old = atomicAdd(done, 1u);
        isLast = (old == gridDim.x - 1u);
    }
    __syncthreads();
    if (!isLast) return;
    __shared__ unsigned int buf[256];
    unsigned int k = st->k;
    unsigned int s = atomicAdd(&ghist[t], 0u);   // atomic read, bypasses L1
    buf[t] = s;
    __syncthreads();
    for (int off = 1; off < 256; off <<= 1) {
        unsigned int v = (t >= off) ? buf[t - off] : 0u;
        __syncthreads();
        buf[t] += v;
        __syncthreads();
    }
    unsigned int incl = buf[t], excl = incl - s;
    if (excl < k && k <= incl) {                 // exactly one thread wins
        st->prefix = (st->prefix << 8) | (unsigned long long)t;
        st->k = k - excl;
    }
    ghist[t] = 0u;                               // ready for next pass/hop
}

__global__ void deg_kernel(const int* __restrict__ dst, int* __restrict__ deg, int E) {
    int e = blockIdx.x * blockDim.x + threadIdx.x;
    if (e < E) atomicAdd(&deg[dst[e]], 1);
}

__global__ void norm_kernel(const int* __restrict__ deg, float* __restrict__ nrm, int N) {
    int i = blockIdx.x * blockDim.x + threadIdx.x;
    if (i < N) nrm[i] = 1.0f / sqrtf(fmaxf((float)deg[i], 1.0f));
}

// ---- parallel exclusive scan of deg (3 kernels) ----
__global__ void blocksum_kernel(const int* __restrict__ deg, int* __restrict__ bsum, int N) {
    int i = blockIdx.x * 256 + threadIdx.x;
    int v = (i < N) ? deg[i] : 0;
#pragma unroll
    for (int off = 32; off > 0; off >>= 1) v += __shfl_down(v, off, 64);
    __shared__ int ws4[4];
    if ((threadIdx.x & 63) == 0) ws4[threadIdx.x >> 6] = v;
    __syncthreads();
    if (threadIdx.x == 0) bsum[blockIdx.x] = ws4[0] + ws4[1] + ws4[2] + ws4[3];
}

__global__ void scanpartial_kernel(const int* __restrict__ bsum, int* __restrict__ boff, int B) {
    __shared__ int buf[512];
    int t = threadIdx.x;
    int v = (t < B) ? bsum[t] : 0;
    buf[t] = v;
    __syncthreads();
    for (int off = 1; off < 512; off <<= 1) {
        int u = (t >= off) ? buf[t - off] : 0;
        __syncthreads();
        buf[t] += u;
        __syncthreads();
    }
    if (t < B) boff[t] = buf[t] - v;   // exclusive
}

__global__ void writeoffs_kernel(const int* __restrict__ deg, const int* __restrict__ boff,
                                 int* __restrict__ offs, int* __restrict__ cursor, int N) {
    __shared__ int buf[256];
    int t = threadIdx.x;
    int i = blockIdx.x * 256 + t;
    int v = (i < N) ? deg[i] : 0;
    buf[t] = v;
    __syncthreads();
    for (int off = 1; off < 256; off <<= 1) {
        int u = (t >= off) ? buf[t - off] : 0;
        __syncthreads();
        buf[t] += u;
        __syncthreads();
    }
    int ex = buf[t] - v + boff[blockIdx.x];
    if (i < N) { offs[i] = ex; cursor[i] = ex; }
    if (i == N - 1) offs[N] = ex + v;   // == E
}

// scatter edges into CSR-by-dst slots; keep original edge id for exact tie-break
__global__ void fill_kernel(const int* __restrict__ src, const int* __restrict__ dst,
                            int* __restrict__ cursor,
                            int* __restrict__ csr_src, int* __restrict__ csr_dst,
                            int* __restrict__ csr_eid, int E) {
    int e = blockIdx.x * blockDim.x + threadIdx.x;
    if (e >= E) return;
    int d = dst[e];
    int pos = atomicAdd(&cursor[d], 1);
    csr_src[pos] = src[e];
    csr_dst[pos] = d;
    csr_eid[pos] = e;
}

// nh = h / max(||h||,1e-12)  AND  hs = h * nrm  (fused); block 0 also resets st
__global__ void rownorm_kernel(const float* __restrict__ h, float* __restrict__ nh,
                               float* __restrict__ hs, const float* __restrict__ nrm,
                               SelState* __restrict__ st, int N) {
    int i = blockIdx.x * blockDim.x + threadIdx.x;
    if (i == 0) { st->prefix = 0ull; st->k = CUT_K; }
    if (i >= N) return;
    const float4* hp = (const float4*)(h + (size_t)i * D_FEAT);
    float4 v[8];
    float ss = 0.f;
#pragma unroll
    for (int q = 0; q < 8; ++q) {
        v[q] = hp[q];
        ss += v[q].x * v[q].x + v[q].y * v[q].y + v[q].z * v[q].z + v[q].w * v[q].w;
    }
    float inv = 1.0f / fmaxf(sqrtf(ss), 1e-12f);
    float sc = nrm[i];
    float4* op = (float4*)(nh + (size_t)i * D_FEAT);
    float4* sp = (float4*)(hs + (size_t)i * D_FEAT);
#pragma unroll
    for (int q = 0; q < 8; ++q) {
        float4 ov = v[q];
        float4 sv = v[q];
        ov.x *= inv; ov.y *= inv; ov.z *= inv; ov.w *= inv;
        sv.x *= sc;  sv.y *= sc;  sv.z *= sc;  sv.w *= sc;
        op[q] = ov;
        sp[q] = sv;
    }
}

// keys[p] = (sortable(cos_p) << 32) | orig_eid; fused pass-0 histogram + elected scan
__global__ void coskey_kernel(const float* __restrict__ nh, const int* __restrict__ csr_src,
                              const int* __restrict__ csr_dst, const int* __restrict__ csr_eid,
                              unsigned long long* __restrict__ keys,
                              unsigned int* __restrict__ ghist, unsigned int* __restrict__ done,
                              SelState* __restrict__ st, int E) {
    __shared__ unsigned int lh[4][256];
    int t = threadIdx.x;
#pragma unroll
    for (int w = 0; w < 4; ++w) lh[w][t] = 0u;
    __syncthreads();
    int wave = t >> 6;
    int stride = gridDim.x * blockDim.x;
    for (int p = blockIdx.x * blockDim.x + t; p < E; p += stride) {
        const float4* a = (const float4*)(nh + (size_t)csr_src[p] * D_FEAT);
        const float4* b = (const float4*)(nh + (size_t)csr_dst[p] * D_FEAT);
        float s = 0.f;
#pragma unroll
        for (int q = 0; q < 8; ++q) {
            float4 x = a[q], y = b[q];
            s += x.x * y.x + x.y * y.y + x.z * y.z + x.w * y.w;
        }
        unsigned int u = __float_as_uint(s);
        unsigned int so = (u & 0x80000000u) ? ~u : (u | 0x80000000u);
        unsigned long long key = ((unsigned long long)so << 32) | (unsigned int)csr_eid[p];
        keys[p] = key;
        atomicAdd(&lh[wave][(unsigned int)(key >> 56)], 1u);
    }
    __syncthreads();
    unsigned int tot = lh[0][t] + lh[1][t] + lh[2][t] + lh[3][t];
    hist_merge_scan(tot, ghist, done, st);
}

// compacting radix pass p (1..7), slice-deterministic, + elected scan in tail
__global__ void histc_kernel(const unsigned long long* __restrict__ in,
                             const int* __restrict__ cnt_in,      // null => dense (pass 1)
                             unsigned long long* __restrict__ out,
                             int* __restrict__ cnt_out,
                             SelState* __restrict__ st,
                             unsigned int* __restrict__ ghist, unsigned int* __restrict__ done,
                             int pass) {
    __shared__ unsigned int lh[4][256];
    __shared__ unsigned int lcnt;
    int t = threadIdx.x, b = blockIdx.x;
#pragma unroll
    for (int w = 0; w < 4; ++w) lh[w][t] = 0u;
    if (t == 0) lcnt = 0u;
    __syncthreads();
    unsigned long long prefix = st->prefix;
    int n = cnt_in ? cnt_in[b] : HC_SLICE;
    const unsigned long long* sin = in + (size_t)b * HC_SLICE;
    unsigned long long* sout = out + (size_t)b * HC_SLICE;
    int wave = t >> 6;
    int fshift = 64 - 8 * pass;
    int dshift = 56 - 8 * pass;
    for (int i = t; i < n; i += 256) {
        unsigned long long key = sin[i];
        if ((key >> fshift) == prefix) {
            atomicAdd(&lh[wave][(unsigned int)((key >> dshift) & 0xFFull)], 1u);
            unsigned int slot = atomicAdd(&lcnt, 1u);   // LDS atomic, block-local
            sout[slot] = key;
        }
    }
    __syncthreads();
    if (t == 0) cnt_out[b] = (int)lcnt;
    unsigned int tot = lh[0][t] + lh[1][t] + lh[2][t] + lh[3][t];
    hist_merge_scan(tot, ghist, done, st);
}

// pull aggregation: one 32-lane group per node walks its CSR segment.
// 8x unrolled with unconditional gathers for memory-level parallelism.
__global__ void aggregate_csr_kernel(const float* __restrict__ hs, float* __restrict__ h_out,
                                     const int* __restrict__ offs, const int* __restrict__ csr_src,
                                     const unsigned long long* __restrict__ keys,
                                     const SelState* __restrict__ st,
                                     const float* __restrict__ nrm, int N) {
    unsigned long long kth = st->prefix;   // cut_k-th smallest composite key
    int g = blockIdx.x * 8 + (threadIdx.x >> 5);
    int j = threadIdx.x & 31;
    if (g >= N) return;
    int lo = offs[g], hi = offs[g + 1];
    float acc = 0.f;
    int p = lo;
    for (; p + 8 <= hi; p += 8) {
        unsigned long long kk[8];
        int ss[8];
#pragma unroll
        for (int u = 0; u < 8; ++u) { kk[u] = keys[p + u]; ss[u] = csr_src[p + u]; }
        float vv[8];
#pragma unroll
        for (int u = 0; u < 8; ++u) vv[u] = hs[(size_t)ss[u] * D_FEAT + j];
#pragma unroll
        for (int u = 0; u < 8; ++u) acc += (kk[u] > kth) ? vv[u] : 0.f;  // same seq FP order
    }
    for (; p < hi; ++p) {
        if (keys[p] > kth) acc += hs[(size_t)csr_src[p] * D_FEAT + j];
    }
    h_out[(size_t)g * D_FEAT + j] = acc * nrm[g];
}

// out = h @ W^T ; stage W transposed in LDS (pad 33, conflict-free)
__global__ void fc_kernel(const float* __restrict__ h, const float* __restrict__ W,
                          float* __restrict__ out, int N) {
    __shared__ float Wt[32][33];
    int t = threadIdx.x;
    for (int i = t; i < 1024; i += 256) Wt[i & 31][i >> 5] = W[i];
    __syncthreads();
    int node = blockIdx.x * 8 + (t >> 5);
    if (node >= N) return;
    int o = t & 31;
    const float* hr = h + (size_t)node * D_FEAT;
    float acc = 0.f;
#pragma unroll
    for (int j = 0; j < 32; ++j) acc += hr[j] * Wt[j][o];
    out[(size_t)node * D_FEAT + o] = acc;
}

extern "C" void kernel_launch(void* const* d_in, const int* in_sizes, int n_in,
                              void* d_out, int out_size, void* d_ws, size_t ws_size,
                              hipStream_t stream) {
    const float* features = (const float*)d_in[0];
    const float* W        = (const float*)d_in[1];
    const int*   src      = (const int*)d_in[2];
    const int*   dst      = (const int*)d_in[3];
    float*       out      = (float*)d_out;

    char* ws = (char*)d_ws;
    size_t o = 0;
    auto take = [&](size_t bytes) -> char* {
        char* p = ws + o;
        o += (bytes + 255) & ~(size_t)255;
        return p;
    };
    int*                deg     = (int*)take((size_t)N_NODES * 4);
    float*              nrm     = (float*)take((size_t)N_NODES * 4);
    int*                offs    = (int*)take((size_t)(N_NODES + 1) * 4);
    int*                cursor  = (int*)take((size_t)N_NODES * 4);
    int*                csr_src = (int*)take((size_t)N_EDGES * 4);
    int*                csr_dst = (int*)take((size_t)N_EDGES * 4);
    int*                csr_eid = (int*)take((size_t)N_EDGES * 4);
    float*              hA      = (float*)take((size_t)N_NODES * D_FEAT * 4);
    float*              hB      = (float*)take((size_t)N_NODES * D_FEAT * 4);
    float*              nh      = (float*)take((size_t)N_NODES * D_FEAT * 4);
    float*              hs      = (float*)take((size_t)N_NODES * D_FEAT * 4);
    unsigned long long* keys    = (unsigned long long*)take((size_t)N_EDGES * 8);
    unsigned int*       ctrl    = (unsigned int*)take((size_t)(256 + 16) * 4); // ghist + done[16]
    SelState*           st      = (SelState*)take(256);
    int*                bsum    = (int*)take((size_t)SCAN_NB * 4);
    int*                boff    = (int*)take((size_t)SCAN_NB * 4);
    int*                cnt_a   = (int*)take((size_t)HC_NB * 4);
    int*                cnt_b   = (int*)take((size_t)HC_NB * 4);

    unsigned int* ghist = ctrl;
    unsigned int* done  = ctrl + 256;   // 16 one-shot pass counters

    // candidate slice buffers alias dead memory during the radix passes:
    // nh is dead after coskey; hB is written only by hop-2 aggregate (after selection).
    unsigned long long* candA = (unsigned long long*)nh;
    unsigned long long* candB = (unsigned long long*)hB;

    hipMemsetAsync(deg, 0, (size_t)N_NODES * 4, stream);
    hipMemsetAsync(ctrl, 0, (size_t)(256 + 16) * 4, stream);

    deg_kernel<<<(N_EDGES + 255) / 256, 256, 0, stream>>>(dst, deg, N_EDGES);
    norm_kernel<<<(N_NODES + 255) / 256, 256, 0, stream>>>(deg, nrm, N_NODES);
    blocksum_kernel<<<SCAN_NB, 256, 0, stream>>>(deg, bsum, N_NODES);
    scanpartial_kernel<<<1, 512, 0, stream>>>(bsum, boff, SCAN_NB);
    writeoffs_kernel<<<SCAN_NB, 256, 0, stream>>>(deg, boff, offs, cursor, N_NODES);
    fill_kernel<<<(N_EDGES + 255) / 256, 256, 0, stream>>>(src, dst, cursor,
                                                           csr_src, csr_dst, csr_eid, N_EDGES);

    const float* hin = features;
    float* houts[2] = { hA, hB };
    for (int hop = 0; hop < 2; ++hop) {
        float* hout = houts[hop];
        rownorm_kernel<<<(N_NODES + 255) / 256, 256, 0, stream>>>(hin, nh, hs, nrm, st, N_NODES);
        coskey_kernel<<<HIST_NB, 256, 0, stream>>>(nh, csr_src, csr_dst, csr_eid,
                                                   keys, ghist, &done[hop * 8], st, N_EDGES);
        for (int pass = 1; pass < 8; ++pass) {
            const unsigned long long* in =
                (pass == 1) ? keys : ((pass & 1) ? candB : candA);
            const int* cin = (pass == 1) ? (const int*)nullptr
                                         : ((pass & 1) ? cnt_b : cnt_a);
            unsigned long long* outc = (pass & 1) ? candA : candB;
            int* cout = (pass & 1) ? cnt_a : cnt_b;
            histc_kernel<<<HC_NB, 256, 0, stream>>>(in, cin, outc, cout, st, ghist,
                                                    &done[hop * 8 + pass], pass);
        }
        aggregate_csr_kernel<<<(N_NODES + 7) / 8, 256, 0, stream>>>(
            hs, hout, offs, csr_src, keys, st, nrm, N_NODES);
        hin = hout;
    }
    fc_kernel<<<(N_NODES + 7) / 8, 256, 0, stream>>>(hin, W, out, N_NODES);
}

// Round 7
// 634.435 us; speedup vs baseline: 2.5219x; 2.5219x over previous
//
#include <hip/hip_runtime.h>
#include <hip/hip_bf16.h>
#include <stdint.h>

#define N_NODES 100000
#define N_EDGES 1600000
#define D_FEAT 32
#define CUT_K 320000        // int(N_EDGES * 0.2)
#define COSKEY_NB 4096      // coskey grid: enough blocks for full occupancy
#define HC_NB 1000          // histc blocks; E = HC_NB * HC_SLICE exactly
#define HC_SLICE 1600
#define SCAN_NB ((N_NODES + 255) / 256)   // 391

struct SelState { unsigned long long prefix; unsigned int k; };

__global__ void deg_kernel(const int* __restrict__ dst, int* __restrict__ deg, int E) {
    int e = blockIdx.x * blockDim.x + threadIdx.x;
    if (e < E) atomicAdd(&deg[dst[e]], 1);
}

__global__ void norm_kernel(const int* __restrict__ deg, float* __restrict__ nrm, int N) {
    int i = blockIdx.x * blockDim.x + threadIdx.x;
    if (i < N) nrm[i] = 1.0f / sqrtf(fmaxf((float)deg[i], 1.0f));
}

// ---- parallel exclusive scan of deg (3 kernels) ----
__global__ void blocksum_kernel(const int* __restrict__ deg, int* __restrict__ bsum, int N) {
    int i = blockIdx.x * 256 + threadIdx.x;
    int v = (i < N) ? deg[i] : 0;
#pragma unroll
    for (int off = 32; off > 0; off >>= 1) v += __shfl_down(v, off, 64);
    __shared__ int ws4[4];
    if ((threadIdx.x & 63) == 0) ws4[threadIdx.x >> 6] = v;
    __syncthreads();
    if (threadIdx.x == 0) bsum[blockIdx.x] = ws4[0] + ws4[1] + ws4[2] + ws4[3];
}

__global__ void scanpartial_kernel(const int* __restrict__ bsum, int* __restrict__ boff, int B) {
    __shared__ int buf[512];
    int t = threadIdx.x;
    int v = (t < B) ? bsum[t] : 0;
    buf[t] = v;
    __syncthreads();
    for (int off = 1; off < 512; off <<= 1) {
        int u = (t >= off) ? buf[t - off] : 0;
        __syncthreads();
        buf[t] += u;
        __syncthreads();
    }
    if (t < B) boff[t] = buf[t] - v;   // exclusive
}

__global__ void writeoffs_kernel(const int* __restrict__ deg, const int* __restrict__ boff,
                                 int* __restrict__ offs, int* __restrict__ cursor, int N) {
    __shared__ int buf[256];
    int t = threadIdx.x;
    int i = blockIdx.x * 256 + t;
    int v = (i < N) ? deg[i] : 0;
    buf[t] = v;
    __syncthreads();
    for (int off = 1; off < 256; off <<= 1) {
        int u = (t >= off) ? buf[t - off] : 0;
        __syncthreads();
        buf[t] += u;
        __syncthreads();
    }
    int ex = buf[t] - v + boff[blockIdx.x];
    if (i < N) { offs[i] = ex; cursor[i] = ex; }
    if (i == N - 1) offs[N] = ex + v;   // == E
}

// scatter edges into CSR-by-dst slots; keep original edge id for exact tie-break
__global__ void fill_kernel(const int* __restrict__ src, const int* __restrict__ dst,
                            int* __restrict__ cursor,
                            int* __restrict__ csr_src, int* __restrict__ csr_dst,
                            int* __restrict__ csr_eid, int E) {
    int e = blockIdx.x * blockDim.x + threadIdx.x;
    if (e >= E) return;
    int d = dst[e];
    int pos = atomicAdd(&cursor[d], 1);
    csr_src[pos] = src[e];
    csr_dst[pos] = d;
    csr_eid[pos] = e;
}

// nh = h / max(||h||,1e-12)  AND  hs = h * nrm  (fused); thread 0 also resets st
__global__ void rownorm_kernel(const float* __restrict__ h, float* __restrict__ nh,
                               float* __restrict__ hs, const float* __restrict__ nrm,
                               SelState* __restrict__ st, int N) {
    int i = blockIdx.x * blockDim.x + threadIdx.x;
    if (i == 0) { st->prefix = 0ull; st->k = CUT_K; }
    if (i >= N) return;
    const float4* hp = (const float4*)(h + (size_t)i * D_FEAT);
    float4 v[8];
    float ss = 0.f;
#pragma unroll
    for (int q = 0; q < 8; ++q) {
        v[q] = hp[q];
        ss += v[q].x * v[q].x + v[q].y * v[q].y + v[q].z * v[q].z + v[q].w * v[q].w;
    }
    float inv = 1.0f / fmaxf(sqrtf(ss), 1e-12f);
    float sc = nrm[i];
    float4* op = (float4*)(nh + (size_t)i * D_FEAT);
    float4* sp = (float4*)(hs + (size_t)i * D_FEAT);
#pragma unroll
    for (int q = 0; q < 8; ++q) {
        float4 ov = v[q];
        float4 sv = v[q];
        ov.x *= inv; ov.y *= inv; ov.z *= inv; ov.w *= inv;
        sv.x *= sc;  sv.y *= sc;  sv.z *= sc;  sv.w *= sc;
        op[q] = ov;
        sp[q] = sv;
    }
}

// keys[p] = (sortable(cos_p) << 32) | orig_eid; fused pass-0 histogram (top 8 bits)
__global__ void coskey_kernel(const float* __restrict__ nh, const int* __restrict__ csr_src,
                              const int* __restrict__ csr_dst, const int* __restrict__ csr_eid,
                              unsigned long long* __restrict__ keys,
                              unsigned int* __restrict__ ghist, int E) {
    __shared__ unsigned int lh[4][256];
    int t = threadIdx.x;
#pragma unroll
    for (int w = 0; w < 4; ++w) lh[w][t] = 0u;
    __syncthreads();
    int wave = t >> 6;
    int stride = gridDim.x * blockDim.x;
    for (int p = blockIdx.x * blockDim.x + t; p < E; p += stride) {
        const float4* a = (const float4*)(nh + (size_t)csr_src[p] * D_FEAT);
        const float4* b = (const float4*)(nh + (size_t)csr_dst[p] * D_FEAT);
        float s = 0.f;
#pragma unroll
        for (int q = 0; q < 8; ++q) {
            float4 x = a[q], y = b[q];
            s += x.x * y.x + x.y * y.y + x.z * y.z + x.w * y.w;
        }
        unsigned int u = __float_as_uint(s);
        unsigned int so = (u & 0x80000000u) ? ~u : (u | 0x80000000u);
        unsigned long long key = ((unsigned long long)so << 32) | (unsigned int)csr_eid[p];
        keys[p] = key;
        atomicAdd(&lh[wave][(unsigned int)(key >> 56)], 1u);
    }
    __syncthreads();
    unsigned int tot = lh[0][t] + lh[1][t] + lh[2][t] + lh[3][t];
    if (tot) atomicAdd(&ghist[t], tot);
}

// compacting radix pass p (1..7), slice-deterministic, NO global atomics except
// the 256-bin ghist merge. Block b: input slice b (dense keys for pass 1),
// survivors appended to its private output slice via an LDS cursor.
__global__ void histc_kernel(const unsigned long long* __restrict__ in,
                             const int* __restrict__ cnt_in,      // null => dense (pass 1)
                             unsigned long long* __restrict__ out,
                             int* __restrict__ cnt_out,
                             const SelState* __restrict__ st,
                             unsigned int* __restrict__ ghist, int pass) {
    __shared__ unsigned int lh[4][256];
    __shared__ unsigned int lcnt;
    int t = threadIdx.x, b = blockIdx.x;
#pragma unroll
    for (int w = 0; w < 4; ++w) lh[w][t] = 0u;
    if (t == 0) lcnt = 0u;
    __syncthreads();
    unsigned long long prefix = st->prefix;
    int n = cnt_in ? cnt_in[b] : HC_SLICE;
    const unsigned long long* sin = in + (size_t)b * HC_SLICE;
    unsigned long long* sout = out + (size_t)b * HC_SLICE;
    int wave = t >> 6;
    int fshift = 64 - 8 * pass;
    int dshift = 56 - 8 * pass;
    for (int i = t; i < n; i += 256) {
        unsigned long long key = sin[i];
        if ((key >> fshift) == prefix) {
            atomicAdd(&lh[wave][(unsigned int)((key >> dshift) & 0xFFull)], 1u);
            unsigned int slot = atomicAdd(&lcnt, 1u);   // LDS atomic, block-local
            sout[slot] = key;
        }
    }
    __syncthreads();
    if (t == 0) cnt_out[b] = (int)lcnt;
    unsigned int tot = lh[0][t] + lh[1][t] + lh[2][t] + lh[3][t];
    if (tot) atomicAdd(&ghist[t], tot);
}

// single block of 256: scan 256-bin global hist, pick digit at rank k, zero hist
__global__ void scan8_kernel(unsigned int* __restrict__ ghist, SelState* __restrict__ st) {
    __shared__ unsigned int buf[256];
    int t = threadIdx.x;
    unsigned int k = st->k;            // read before any write
    unsigned int s = ghist[t];
    buf[t] = s;
    __syncthreads();
    for (int off = 1; off < 256; off <<= 1) {
        unsigned int v = (t >= off) ? buf[t - off] : 0u;
        __syncthreads();
        buf[t] += v;
        __syncthreads();
    }
    unsigned int incl = buf[t];
    unsigned int excl = incl - s;
    if (excl < k && k <= incl) {       // exactly one thread wins
        st->prefix = (st->prefix << 8) | (unsigned long long)t;
        st->k = k - excl;
    }
    ghist[t] = 0u;                     // ready for next pass/hop
}

// pull aggregation: one 32-lane group per node walks its CSR segment.
// 8x unrolled with unconditional gathers for memory-level parallelism.
__global__ void aggregate_csr_kernel(const float* __restrict__ hs, float* __restrict__ h_out,
                                     const int* __restrict__ offs, const int* __restrict__ csr_src,
                                     const unsigned long long* __restrict__ keys,
                                     const SelState* __restrict__ st,
                                     const float* __restrict__ nrm, int N) {
    unsigned long long kth = st->prefix;   // cut_k-th smallest composite key
    int g = blockIdx.x * 8 + (threadIdx.x >> 5);
    int j = threadIdx.x & 31;
    if (g >= N) return;
    int lo = offs[g], hi = offs[g + 1];
    float acc = 0.f;
    int p = lo;
    for (; p + 8 <= hi; p += 8) {
        unsigned long long kk[8];
        int ss[8];
#pragma unroll
        for (int u = 0; u < 8; ++u) { kk[u] = keys[p + u]; ss[u] = csr_src[p + u]; }
        float vv[8];
#pragma unroll
        for (int u = 0; u < 8; ++u) vv[u] = hs[(size_t)ss[u] * D_FEAT + j];
#pragma unroll
        for (int u = 0; u < 8; ++u) acc += (kk[u] > kth) ? vv[u] : 0.f;  // same seq FP order
    }
    for (; p < hi; ++p) {
        if (keys[p] > kth) acc += hs[(size_t)csr_src[p] * D_FEAT + j];
    }
    h_out[(size_t)g * D_FEAT + j] = acc * nrm[g];
}

// out = h @ W^T ; stage W transposed in LDS (pad 33, conflict-free)
__global__ void fc_kernel(const float* __restrict__ h, const float* __restrict__ W,
                          float* __restrict__ out, int N) {
    __shared__ float Wt[32][33];
    int t = threadIdx.x;
    for (int i = t; i < 1024; i += 256) Wt[i & 31][i >> 5] = W[i];
    __syncthreads();
    int node = blockIdx.x * 8 + (t >> 5);
    if (node >= N) return;
    int o = t & 31;
    const float* hr = h + (size_t)node * D_FEAT;
    float acc = 0.f;
#pragma unroll
    for (int j = 0; j < 32; ++j) acc += hr[j] * Wt[j][o];
    out[(size_t)node * D_FEAT + o] = acc;
}

extern "C" void kernel_launch(void* const* d_in, const int* in_sizes, int n_in,
                              void* d_out, int out_size, void* d_ws, size_t ws_size,
                              hipStream_t stream) {
    const float* features = (const float*)d_in[0];
    const float* W        = (const float*)d_in[1];
    const int*   src      = (const int*)d_in[2];
    const int*   dst      = (const int*)d_in[3];
    float*       out      = (float*)d_out;

    char* ws = (char*)d_ws;
    size_t o = 0;
    auto take = [&](size_t bytes) -> char* {
        char* p = ws + o;
        o += (bytes + 255) & ~(size_t)255;
        return p;
    };
    int*                deg     = (int*)take((size_t)N_NODES * 4);
    float*              nrm     = (float*)take((size_t)N_NODES * 4);
    int*                offs    = (int*)take((size_t)(N_NODES + 1) * 4);
    int*                cursor  = (int*)take((size_t)N_NODES * 4);
    int*                csr_src = (int*)take((size_t)N_EDGES * 4);
    int*                csr_dst = (int*)take((size_t)N_EDGES * 4);
    int*                csr_eid = (int*)take((size_t)N_EDGES * 4);
    float*              hA      = (float*)take((size_t)N_NODES * D_FEAT * 4);
    float*              hB      = (float*)take((size_t)N_NODES * D_FEAT * 4);
    float*              nh      = (float*)take((size_t)N_NODES * D_FEAT * 4);
    float*              hs      = (float*)take((size_t)N_NODES * D_FEAT * 4);
    unsigned long long* keys    = (unsigned long long*)take((size_t)N_EDGES * 8);
    unsigned int*       ghist   = (unsigned int*)take((size_t)256 * 4);
    SelState*           st      = (SelState*)take(256);
    int*                bsum    = (int*)take((size_t)SCAN_NB * 4);
    int*                boff    = (int*)take((size_t)SCAN_NB * 4);
    int*                cnt_a   = (int*)take((size_t)HC_NB * 4);
    int*                cnt_b   = (int*)take((size_t)HC_NB * 4);

    // candidate slice buffers alias dead memory during the radix passes:
    // nh is dead after coskey; hB is written only by hop-2 aggregate (after selection).
    unsigned long long* candA = (unsigned long long*)nh;
    unsigned long long* candB = (unsigned long long*)hB;

    hipMemsetAsync(deg, 0, (size_t)N_NODES * 4, stream);
    hipMemsetAsync(ghist, 0, (size_t)256 * 4, stream);

    deg_kernel<<<(N_EDGES + 255) / 256, 256, 0, stream>>>(dst, deg, N_EDGES);
    norm_kernel<<<(N_NODES + 255) / 256, 256, 0, stream>>>(deg, nrm, N_NODES);
    blocksum_kernel<<<SCAN_NB, 256, 0, stream>>>(deg, bsum, N_NODES);
    scanpartial_kernel<<<1, 512, 0, stream>>>(bsum, boff, SCAN_NB);
    writeoffs_kernel<<<SCAN_NB, 256, 0, stream>>>(deg, boff, offs, cursor, N_NODES);
    fill_kernel<<<(N_EDGES + 255) / 256, 256, 0, stream>>>(src, dst, cursor,
                                                           csr_src, csr_dst, csr_eid, N_EDGES);

    const float* hin = features;
    float* houts[2] = { hA, hB };
    for (int hop = 0; hop < 2; ++hop) {
        float* hout = houts[hop];
        rownorm_kernel<<<(N_NODES + 255) / 256, 256, 0, stream>>>(hin, nh, hs, nrm, st, N_NODES);
        coskey_kernel<<<COSKEY_NB, 256, 0, stream>>>(nh, csr_src, csr_dst, csr_eid,
                                                     keys, ghist, N_EDGES);
        scan8_kernel<<<1, 256, 0, stream>>>(ghist, st);   // digit 0
        for (int pass = 1; pass < 8; ++pass) {
            const unsigned long long* in =
                (pass == 1) ? keys : ((pass & 1) ? candB : candA);
            const int* cin = (pass == 1) ? (const int*)nullptr
                                         : ((pass & 1) ? cnt_b : cnt_a);
            unsigned long long* outc = (pass & 1) ? candA : candB;
            int* cout = (pass & 1) ? cnt_a : cnt_b;
            histc_kernel<<<HC_NB, 256, 0, stream>>>(in, cin, outc, cout, st, ghist, pass);
            scan8_kernel<<<1, 256, 0, stream>>>(ghist, st);
        }
        aggregate_csr_kernel<<<(N_NODES + 7) / 8, 256, 0, stream>>>(
            hs, hout, offs, csr_src, keys, st, nrm, N_NODES);
        hin = hout;
    }
    fc_kernel<<<(N_NODES + 7) / 8, 256, 0, stream>>>(hin, W, out, N_NODES);
}